// Round 4
// baseline (238.307 us; speedup 1.0000x reference)
//
#include <hip/hip_runtime.h>
#include <cstddef>
#include <cstring>

// Problem constants (setup_inputs is fixed):
//   feats: (B=4, C=256, H=160, W=160) float32  = 105 MB
//   rois:  (N=512, 5) float32  [batch, x1, y1, x2, y2] (normalized, scale=160)
//   out:   (N, C, OH=14, OW=14) float32        = 103 MB
//
// R2: cg slow axis + XCD slicing -> fetch 359->46 MB.    (131 -> 108 us)
// R3: float2 x-pair gathers, K=8.                        (108 -> 91 us)
//     Post-mortem: bound by TA/L1 transaction splitting of divergent gathers
//     (NCHW: channels 102 KB apart -> no cross-lane coalescing possible).
// R4: layout transform. Kernel 1: NCHW f32 -> NHWC bf16 in d_ws (52.4 MB).
//     Kernel 2: one block per (n, oy); a corner load = 64 lanes x 4bf16 =
//     512 B fully coalesced; LDS-stage [ox][c], write out (c,ox)-linear.
#define RA_B  4
#define RA_C  256
#define RA_H  160
#define RA_W  160
#define RA_OH 14
#define RA_OW 14
#define RA_SCALE 160.0f
#define RA_NXCD 8

#define RA_HW   (RA_H * RA_W)          // 25600
#define WS_BYTES ((size_t)RA_B * RA_HW * RA_C * 2)   // 52,428,800

// ---- bf16 helpers (bit-level, RNE) ----
__device__ __forceinline__ unsigned short f2bf(float f) {
    unsigned int u; __builtin_memcpy(&u, &f, 4);
    unsigned int lsb = (u >> 16) & 1u;
    u += 0x7fffu + lsb;                 // round-to-nearest-even
    return (unsigned short)(u >> 16);
}
__device__ __forceinline__ float bf2f(unsigned short h) {
    unsigned int u = ((unsigned int)h) << 16;
    float f; __builtin_memcpy(&f, &u, 4);
    return f;
}

// ============================================================================
// Kernel 1: transpose (B,C,H,W) f32  ->  (B,HW,C) bf16
// 64x64 tiles, LDS staged, coalesced on both sides. Covers every ws element.
// ============================================================================
__global__ __launch_bounds__(256) void nchw_to_nhwc_bf16(
    const float* __restrict__ in,          // [B][C][HW]
    unsigned short* __restrict__ wsb)      // [B][HW][C] bf16 bits
{
    constexpr int MT = RA_HW / 64;         // 400 hw-tiles
    constexpr int CT = RA_C / 64;          // 4 c-tiles

    int bid  = blockIdx.x;
    int mt   = bid % MT;
    int rest = bid / MT;
    int ct   = rest % CT;
    int b    = rest / CT;

    __shared__ float tile[64][65];         // [c_local][hw_local], pad 65

    int t  = threadIdx.x;
    int tx = t & 63;                       // hw_local on load
    int ty = t >> 6;                       // 0..3

    const float* src = in + ((size_t)b * RA_C + (size_t)ct * 64) * RA_HW
                          + (size_t)mt * 64;
#pragma unroll
    for (int i = 0; i < 16; ++i) {
        int cl = ty + 4 * i;               // 0..63
        tile[cl][tx] = src[(size_t)cl * RA_HW + tx];
    }
    __syncthreads();

    unsigned short* dst = wsb + ((size_t)b * RA_HW + (size_t)mt * 64) * RA_C
                              + (size_t)ct * 64;
    int cx = (t & 31) * 2;                 // c pair
    int mq = t >> 5;                       // 0..7
#pragma unroll
    for (int i = 0; i < 8; ++i) {
        int ml = mq + 8 * i;               // 0..63
        unsigned int lo = f2bf(tile[cx][ml]);
        unsigned int hi = f2bf(tile[cx + 1][ml]);
        unsigned int pk = lo | (hi << 16);
        unsigned int* p = (unsigned int*)(dst + (size_t)ml * RA_C + cx);
        *p = pk;
    }
}

// ============================================================================
// Kernel 2: RoI align from NHWC bf16. One block (256 thr) per (n, oy).
// Wave w handles ox = w, w+4, ...; lane l handles channels 4l..4l+3.
// ============================================================================
__global__ __launch_bounds__(256) void roi_align_nhwc(
    const unsigned short* __restrict__ wsb,   // [B][H][W][C] bf16
    const float* __restrict__ rois,
    float* __restrict__ out,
    int N)
{
    constexpr int S   = RA_OH * RA_OW;     // 196
    constexpr int C   = RA_C;
    constexpr int PAD = 260;               // lds ox-stride (floats), 16B-aligned
    __shared__ float lds[RA_OW * PAD];     // [ox][c]

    // XCD-aware: all 14 oy of a roi land on one XCD (bid round-robin % 8).
    int bid   = blockIdx.x;
    int xcd   = bid & (RA_NXCD - 1);
    int local = bid >> 3;                  // 0 .. N/8*14 - 1
    int nw    = local / RA_OH;
    int oy    = local - nw * RA_OH;
    int n     = nw * RA_NXCD + xcd;

    const float* r = rois + (size_t)n * 5;
    int   b  = (int)r[0];
    float x1 = r[1] * RA_SCALE;
    float y1 = r[2] * RA_SCALE;
    float rw = r[3] * RA_SCALE - x1;
    float rh = r[4] * RA_SCALE - y1;

    // y-interpolation terms (uniform over the block)
    float gy  = (float)oy * (1.0f / (RA_OH - 1));
    float fy  = y1 + gy * rh;
    float nfy = fy / (float)RA_H * 2.0f - 1.0f;
    float iy  = ((nfy + 1.0f) * (float)RA_H - 1.0f) * 0.5f;
    float y0f = floorf(iy);
    int   y0  = (int)y0f;
    float wy1 = iy - y0f, wy0 = 1.0f - wy1;
    bool  vy0 = (y0 >= 0) && (y0 < RA_H);
    bool  vy1 = (y0 + 1 >= 0) && (y0 + 1 < RA_H);
    int   y0c = min(max(y0, 0), RA_H - 1);
    int   y1c = min(max(y0 + 1, 0), RA_H - 1);

    int wave = (int)threadIdx.x >> 6;
    int lane = (int)threadIdx.x & 63;

    const unsigned short* fbase = wsb + (size_t)b * RA_HW * C;

    for (int ox = wave; ox < RA_OW; ox += 4) {
        float gx  = (float)ox * (1.0f / (RA_OW - 1));
        float fx  = x1 + gx * rw;
        float nfx = fx / (float)RA_W * 2.0f - 1.0f;
        float ix  = ((nfx + 1.0f) * (float)RA_W - 1.0f) * 0.5f;
        float x0f = floorf(ix);
        int   x0  = (int)x0f;
        float wx1 = ix - x0f, wx0 = 1.0f - wx1;
        bool  vx0 = (x0 >= 0) && (x0 < RA_W);
        bool  vx1 = (x0 + 1 >= 0) && (x0 + 1 < RA_W);
        int   x0c = min(max(x0, 0), RA_W - 1);
        int   x1c = min(max(x0 + 1, 0), RA_W - 1);

        float w00 = wy0 * wx0 * ((vy0 && vx0) ? 1.0f : 0.0f);
        float w01 = wy0 * wx1 * ((vy0 && vx1) ? 1.0f : 0.0f);
        float w10 = wy1 * wx0 * ((vy1 && vx0) ? 1.0f : 0.0f);
        float w11 = wy1 * wx1 * ((vy1 && vx1) ? 1.0f : 0.0f);

        const unsigned short* p00 = fbase + ((size_t)(y0c * RA_W + x0c)) * C + 4 * lane;
        const unsigned short* p01 = fbase + ((size_t)(y0c * RA_W + x1c)) * C + 4 * lane;
        const unsigned short* p10 = fbase + ((size_t)(y1c * RA_W + x0c)) * C + 4 * lane;
        const unsigned short* p11 = fbase + ((size_t)(y1c * RA_W + x1c)) * C + 4 * lane;

        ushort4 q00, q01, q10, q11;
        __builtin_memcpy(&q00, p00, 8);
        __builtin_memcpy(&q01, p01, 8);
        __builtin_memcpy(&q10, p10, 8);
        __builtin_memcpy(&q11, p11, 8);

        float4 acc;
        acc.x = w00 * bf2f(q00.x) + w01 * bf2f(q01.x) + w10 * bf2f(q10.x) + w11 * bf2f(q11.x);
        acc.y = w00 * bf2f(q00.y) + w01 * bf2f(q01.y) + w10 * bf2f(q10.y) + w11 * bf2f(q11.y);
        acc.z = w00 * bf2f(q00.z) + w01 * bf2f(q01.z) + w10 * bf2f(q10.z) + w11 * bf2f(q11.z);
        acc.w = w00 * bf2f(q00.w) + w01 * bf2f(q01.w) + w10 * bf2f(q10.w) + w11 * bf2f(q11.w);

        *(float4*)&lds[ox * PAD + 4 * lane] = acc;   // 16B-aligned (PAD%4==0)
    }
    __syncthreads();

    // Write out: linear over (c, ox-pairs); runs of 14 floats per c, float2.
    float* ob = out + (size_t)n * C * S + (size_t)oy * RA_OW;
#pragma unroll
    for (int i = 0; i < 7; ++i) {
        int e2 = 2 * ((int)threadIdx.x + 256 * i);  // 0,2,..,3582
        int c  = e2 / 14;
        int ox = e2 - c * 14;                       // even, pair stays in-run
        float2 v;
        v.x = lds[ox * PAD + c];
        v.y = lds[(ox + 1) * PAD + c];
        *(float2*)(ob + (size_t)c * S + ox) = v;    // 8B-aligned
    }
}

// ============================================================================
// Fallback (R3 kernel) — used if ws too small / unexpected shape.
// ============================================================================
#define RA_K  8
__device__ __forceinline__ float2 ldg_f2(const float* p) {
    float2 r; __builtin_memcpy(&r, p, sizeof(float2)); return r;
}

__global__ __launch_bounds__(256) void roi_align_fallback(
    const float* __restrict__ feats,
    const float* __restrict__ rois,
    float* __restrict__ out,
    int N, int bpc)
{
    constexpr int S   = RA_OH * RA_OW;
    constexpr int CG  = RA_C / RA_K;
    constexpr int CGX = CG / RA_NXCD;
    constexpr int HW  = RA_H * RA_W;

    int bid   = blockIdx.x;
    int xcd   = bid & (RA_NXCD - 1);
    int local = bid >> 3;
    int cg    = xcd * CGX + local / bpc;
    int rem   = local - (local / bpc) * bpc;

    int idx_in_cg = rem * 256 + (int)threadIdx.x;
    if (idx_in_cg >= N * S) return;

    int n = idx_in_cg / S;
    int s = idx_in_cg - n * S;
    int oy = s / RA_OW;
    int ox = s - oy * RA_OW;

    const float* r = rois + (size_t)n * 5;
    int   b  = (int)r[0];
    float x1 = r[1] * RA_SCALE;
    float y1 = r[2] * RA_SCALE;
    float rw = r[3] * RA_SCALE - x1;
    float rh = r[4] * RA_SCALE - y1;

    float gx = (float)ox * (1.0f / (RA_OW - 1));
    float gy = (float)oy * (1.0f / (RA_OH - 1));
    float fx = x1 + gx * rw;
    float fy = y1 + gy * rh;

    float nfx = fx / (float)RA_W * 2.0f - 1.0f;
    float nfy = fy / (float)RA_H * 2.0f - 1.0f;
    float ix  = ((nfx + 1.0f) * (float)RA_W - 1.0f) * 0.5f;
    float iy  = ((nfy + 1.0f) * (float)RA_H - 1.0f) * 0.5f;

    float x0f = floorf(ix), y0f = floorf(iy);
    int   x0  = (int)x0f,   y0  = (int)y0f;
    float wx1 = ix - x0f,   wx0 = 1.0f - wx1;
    float wy1 = iy - y0f,   wy0 = 1.0f - wy1;

    int xp = x0 + 1, yp = y0 + 1;
    bool vx0 = (x0 >= 0) && (x0 < RA_W);
    bool vx1 = (xp >= 0) && (xp < RA_W);
    bool vy0 = (y0 >= 0) && (y0 < RA_H);
    bool vy1 = (yp >= 0) && (yp < RA_H);

    float w00 = wy0 * wx0 * ((vy0 && vx0) ? 1.0f : 0.0f);
    float w01 = wy0 * wx1 * ((vy0 && vx1) ? 1.0f : 0.0f);
    float w10 = wy1 * wx0 * ((vy1 && vx0) ? 1.0f : 0.0f);
    float w11 = wy1 * wx1 * ((vy1 && vx1) ? 1.0f : 0.0f);

    int  px  = min(max(x0, 0), RA_W - 2);
    bool swp = (x0 != px);
    float a0 = swp ? w01 : w00;
    float b0 = swp ? w00 : w01;
    float a1 = swp ? w11 : w10;
    float b1 = swp ? w10 : w11;

    int y0c = min(max(y0, 0), RA_H - 1);
    int y1c = min(max(yp, 0), RA_H - 1);
    int o0  = y0c * RA_W + px;
    int o1  = y1c * RA_W + px;

    int c0 = cg * RA_K;
    const float* fb = feats + ((size_t)b * RA_C + c0) * HW;
    float*       op = out   + ((size_t)n * RA_C + c0) * S + s;

#pragma unroll
    for (int k = 0; k < RA_K; ++k) {
        const float* f = fb + (size_t)k * HW;
        float2 p0 = ldg_f2(f + o0);
        float2 p1 = ldg_f2(f + o1);
        float v = fmaf(a0, p0.x, fmaf(b0, p0.y, fmaf(a1, p1.x, b1 * p1.y)));
        op[(size_t)k * S] = v;
    }
}

extern "C" void kernel_launch(void* const* d_in, const int* in_sizes, int n_in,
                              void* d_out, int out_size, void* d_ws, size_t ws_size,
                              hipStream_t stream) {
    const float* feats = (const float*)d_in[0];
    const float* rois  = (const float*)d_in[1];
    float*       out   = (float*)d_out;

    int N = in_sizes[1] / 5;

    bool fast = (in_sizes[0] == RA_B * RA_C * RA_HW)
             && (N % RA_NXCD == 0)
             && (ws_size >= WS_BYTES);

    if (fast) {
        unsigned short* wsb = (unsigned short*)d_ws;
        int tgrid = RA_B * (RA_C / 64) * (RA_HW / 64);   // 6400
        nchw_to_nhwc_bf16<<<tgrid, 256, 0, stream>>>(feats, wsb);
        roi_align_nhwc<<<N * RA_OH, 256, 0, stream>>>(wsb, rois, out, N);
    } else {
        constexpr int S  = RA_OH * RA_OW;
        constexpr int CG = RA_C / RA_K;
        int bpc  = (N * S + 255) / 256;
        int grid = CG * bpc;
        roi_align_fallback<<<grid, 256, 0, stream>>>(feats, rois, out, N, bpc);
    }
}